// Round 1
// baseline (1608.452 us; speedup 1.0000x reference)
//
#include <hip/hip_runtime.h>
#include <math.h>

#define DD 120
#define PP 8
#define NT 128
#define NHEADS 8
#define HDIM 15
#define HASH_MASK 1048575LL
#define MODT 201

// ---------------------------------------------------------------------------
// Projection passes: thread n (n < 120) computes output feature n for all PP
// points, accumulating in registers. Input rows live in LDS; reads are
// wave-uniform broadcasts (ds_read_b128). W rows are read coalesced across
// lanes (L2-resident, 460 KB total weights).
// ---------------------------------------------------------------------------

__device__ __forceinline__ void proj3(const float (*IN)[DD],
    const float* __restrict__ W0, const float* __restrict__ W1, const float* __restrict__ W2,
    const float* __restrict__ b0, const float* __restrict__ b1, const float* __restrict__ b2,
    float (*O0)[DD], float (*O1)[DD], float (*O2)[DD], int n)
{
    float a0[PP], a1[PP], a2[PP];
    {
        float t0 = b0[n], t1 = b1[n], t2 = b2[n];
#pragma unroll
        for (int p = 0; p < PP; p++) { a0[p] = t0; a1[p] = t1; a2[p] = t2; }
    }
    for (int k = 0; k < DD; k += 4) {
        const float* w0p = W0 + k * DD + n;
        const float* w1p = W1 + k * DD + n;
        const float* w2p = W2 + k * DD + n;
        float w00 = w0p[0], w01 = w0p[DD], w02 = w0p[2 * DD], w03 = w0p[3 * DD];
        float w10 = w1p[0], w11 = w1p[DD], w12 = w1p[2 * DD], w13 = w1p[3 * DD];
        float w20 = w2p[0], w21 = w2p[DD], w22 = w2p[2 * DD], w23 = w2p[3 * DD];
#pragma unroll
        for (int p = 0; p < PP; p++) {
            float4 x = *(const float4*)&IN[p][k];
            a0[p] = fmaf(x.x, w00, fmaf(x.y, w01, fmaf(x.z, w02, fmaf(x.w, w03, a0[p]))));
            a1[p] = fmaf(x.x, w10, fmaf(x.y, w11, fmaf(x.z, w12, fmaf(x.w, w13, a1[p]))));
            a2[p] = fmaf(x.x, w20, fmaf(x.y, w21, fmaf(x.z, w22, fmaf(x.w, w23, a2[p]))));
        }
    }
#pragma unroll
    for (int p = 0; p < PP; p++) { O0[p][n] = a0[p]; O1[p][n] = a1[p]; O2[p][n] = a2[p]; }
}

__device__ __forceinline__ void proj2(const float (*IN)[DD],
    const float* __restrict__ W0, const float* __restrict__ W1,
    const float* __restrict__ b0, const float* __restrict__ b1,
    float (*O0)[DD], float (*O1)[DD], int n)
{
    float a0[PP], a1[PP];
    {
        float t0 = b0[n], t1 = b1[n];
#pragma unroll
        for (int p = 0; p < PP; p++) { a0[p] = t0; a1[p] = t1; }
    }
    for (int k = 0; k < DD; k += 4) {
        const float* w0p = W0 + k * DD + n;
        const float* w1p = W1 + k * DD + n;
        float w00 = w0p[0], w01 = w0p[DD], w02 = w0p[2 * DD], w03 = w0p[3 * DD];
        float w10 = w1p[0], w11 = w1p[DD], w12 = w1p[2 * DD], w13 = w1p[3 * DD];
#pragma unroll
        for (int p = 0; p < PP; p++) {
            float4 x = *(const float4*)&IN[p][k];
            a0[p] = fmaf(x.x, w00, fmaf(x.y, w01, fmaf(x.z, w02, fmaf(x.w, w03, a0[p]))));
            a1[p] = fmaf(x.x, w10, fmaf(x.y, w11, fmaf(x.z, w12, fmaf(x.w, w13, a1[p]))));
        }
    }
#pragma unroll
    for (int p = 0; p < PP; p++) { O0[p][n] = a0[p]; O1[p][n] = a1[p]; }
}

__device__ __forceinline__ void proj1(const float (*IN)[DD],
    const float* __restrict__ W0, const float* __restrict__ b0,
    float (*O0)[DD], int n)
{
    float a0[PP];
    {
        float t0 = b0[n];
#pragma unroll
        for (int p = 0; p < PP; p++) a0[p] = t0;
    }
    for (int k = 0; k < DD; k += 4) {
        const float* w0p = W0 + k * DD + n;
        float w00 = w0p[0], w01 = w0p[DD], w02 = w0p[2 * DD], w03 = w0p[3 * DD];
#pragma unroll
        for (int p = 0; p < PP; p++) {
            float4 x = *(const float4*)&IN[p][k];
            a0[p] = fmaf(x.x, w00, fmaf(x.y, w01, fmaf(x.z, w02, fmaf(x.w, w03, a0[p]))));
        }
    }
#pragma unroll
    for (int p = 0; p < PP; p++) O0[p][n] = a0[p];
}

__global__ __launch_bounds__(NT)
void voxel_fused_kernel(const float* __restrict__ pts,
                        const int* __restrict__ times,
                        const int* __restrict__ vox_buf,
                        const float* __restrict__ stat_f,
                        const float* __restrict__ dyn_f,
                        const float* __restrict__ temb,
                        const float* __restrict__ td_w,
                        const float* __restrict__ td_b,
                        const float* __restrict__ sd_w,
                        const float* __restrict__ sd_b,
                        float* __restrict__ out,
                        int Mpts)
{
    __shared__ float A[PP][DD];    // df, later sf
    __shared__ float Bb[PP][DD];   // te, later cond
    __shared__ float Q[PP][DD];
    __shared__ float K0[PP][DD];
    __shared__ float K1[PP][DD];
    __shared__ float V0[PP][DD];
    __shared__ float V1[PP][DD];
    __shared__ float O0[PP][DD];
    __shared__ float sP0[PP][NHEADS];
    __shared__ int s_vi[PP];
    __shared__ int s_valid[PP];
    __shared__ int s_ti[PP];

    const int tid = threadIdx.x;
    const int pbase = blockIdx.x * PP;
    const int n = tid;
    const bool act = (n < DD);

    // ---- per-point meta: hash -> voxel index, time index -------------------
    if (tid < PP) {
        int p = pbase + tid;
        int vi = 0, valid = 0, ti = 0;
        if (p < Mpts) {
            float x = pts[3 * p + 0];
            float y = pts[3 * p + 1];
            float z = pts[3 * p + 2];
            long long gx = (long long)floorf(x / 0.1f);
            long long gy = (long long)floorf(y / 0.1f);
            long long gz = (long long)floorf(z / 0.1f);
            long long h = (gx * 73856093LL + gy * 19349669LL + gz * 83492791LL) & HASH_MASK;
            int v = vox_buf[(int)h];
            valid = (v >= 0) ? 1 : 0;
            vi = (v >= 0) ? v : 0;
            ti = times[p] % MODT;
        }
        s_vi[tid] = vi; s_valid[tid] = valid; s_ti[tid] = ti;
    }
    __syncthreads();

    // ---- gather df -> A, te -> Bb (float4, rows are 480 B, 16B-aligned) ----
    for (int i = tid; i < PP * 30; i += NT) {
        int p = i / 30, f = i % 30;
        ((float4*)&A[p][0])[f]  = ((const float4*)(dyn_f + (size_t)s_vi[p] * DD))[f];
        ((float4*)&Bb[p][0])[f] = ((const float4*)(temb  + (size_t)s_ti[p] * DD))[f];
    }
    __syncthreads();

    // ---- fusion 1 projections: q0,k0,v0 from df; k1,v1 from te -------------
    if (act) {
        proj3(A,  td_w + 0 * DD * DD, td_w + 1 * DD * DD, td_w + 2 * DD * DD,
                  td_b + 0 * DD,      td_b + 1 * DD,      td_b + 2 * DD,
                  Q, K0, V0, n);
        proj2(Bb, td_w + 1 * DD * DD, td_w + 2 * DD * DD,
                  td_b + 1 * DD,      td_b + 2 * DD,
                  K1, V1, n);
    }
    __syncthreads();

    // ---- attention 1, scores + softmax (one thread per point*head) --------
    if (tid < PP * NHEADS) {
        int p = tid >> 3, h = tid & 7;
        const float scale = 0.2581988897471611f; // 1/sqrt(15)
        float s0 = 0.f, s1 = 0.f;
#pragma unroll
        for (int j = 0; j < HDIM; j++) {
            float q = Q[p][h * HDIM + j];
            s0 = fmaf(q, K0[p][h * HDIM + j], s0);
            s1 = fmaf(q, K1[p][h * HDIM + j], s1);
        }
        s0 *= scale; s1 *= scale;
        float mx = fmaxf(s0, s1);
        float e0 = expf(s0 - mx), e1 = expf(s1 - mx);
        sP0[p][h] = e0 / (e0 + e1);
    }
    __syncthreads();

    // ---- attention 1 combine -> O0; also gather sf into A (df is dead) ----
    if (act) {
        int h = n / HDIM;
#pragma unroll
        for (int p = 0; p < PP; p++) {
            float p0 = sP0[p][h];
            O0[p][n] = p0 * V0[p][n] + (1.f - p0) * V1[p][n];
        }
    }
    for (int i = tid; i < PP * 30; i += NT) {
        int p = i / 30, f = i % 30;
        ((float4*)&A[p][0])[f] = ((const float4*)(stat_f + (size_t)s_vi[p] * DD))[f];
    }
    __syncthreads();

    // ---- cond = O0 @ Wtd3 + b (into Bb); q0,k0,v0 of fusion 2 from sf -----
    if (act) {
        proj1(O0, td_w + 3 * DD * DD, td_b + 3 * DD, Bb, n);
        proj3(A,  sd_w + 0 * DD * DD, sd_w + 1 * DD * DD, sd_w + 2 * DD * DD,
                  sd_b + 0 * DD,      sd_b + 1 * DD,      sd_b + 2 * DD,
                  Q, K0, V0, n);
    }
    __syncthreads();

    // ---- k1,v1 of fusion 2 from cond --------------------------------------
    if (act) {
        proj2(Bb, sd_w + 1 * DD * DD, sd_w + 2 * DD * DD,
                  sd_b + 1 * DD,      sd_b + 2 * DD,
                  K1, V1, n);
    }
    __syncthreads();

    // ---- attention 2 -------------------------------------------------------
    if (tid < PP * NHEADS) {
        int p = tid >> 3, h = tid & 7;
        const float scale = 0.2581988897471611f;
        float s0 = 0.f, s1 = 0.f;
#pragma unroll
        for (int j = 0; j < HDIM; j++) {
            float q = Q[p][h * HDIM + j];
            s0 = fmaf(q, K0[p][h * HDIM + j], s0);
            s1 = fmaf(q, K1[p][h * HDIM + j], s1);
        }
        s0 *= scale; s1 *= scale;
        float mx = fmaxf(s0, s1);
        float e0 = expf(s0 - mx), e1 = expf(s1 - mx);
        sP0[p][h] = e0 / (e0 + e1);
    }
    __syncthreads();

    if (act) {
        int h = n / HDIM;
#pragma unroll
        for (int p = 0; p < PP; p++) {
            float p0 = sP0[p][h];
            O0[p][n] = p0 * V0[p][n] + (1.f - p0) * V1[p][n];
        }
    }
    __syncthreads();

    // ---- final: out = O0 @ Wsd3 + b, masked by valid -----------------------
    if (act) {
        float acc[PP];
        {
            float t = sd_b[3 * DD + n];
#pragma unroll
            for (int p = 0; p < PP; p++) acc[p] = t;
        }
        const float* W = sd_w + 3 * DD * DD;
        for (int k = 0; k < DD; k += 4) {
            const float* wp = W + k * DD + n;
            float w0 = wp[0], w1 = wp[DD], w2 = wp[2 * DD], w3 = wp[3 * DD];
#pragma unroll
            for (int p = 0; p < PP; p++) {
                float4 x = *(const float4*)&O0[p][k];
                acc[p] = fmaf(x.x, w0, fmaf(x.y, w1, fmaf(x.z, w2, fmaf(x.w, w3, acc[p]))));
            }
        }
#pragma unroll
        for (int p = 0; p < PP; p++) {
            int gp = pbase + p;
            if (gp < Mpts) {
                out[(size_t)gp * DD + n] = s_valid[p] ? acc[p] : 0.f;
            }
        }
    }
}

extern "C" void kernel_launch(void* const* d_in, const int* in_sizes, int n_in,
                              void* d_out, int out_size, void* d_ws, size_t ws_size,
                              hipStream_t stream) {
    const float* pts   = (const float*)d_in[0];
    const int*   times = (const int*)d_in[1];
    const int*   vox   = (const int*)d_in[2];
    const float* statf = (const float*)d_in[3];
    const float* dynf  = (const float*)d_in[4];
    const float* temb  = (const float*)d_in[5];
    const float* td_w  = (const float*)d_in[6];
    const float* td_b  = (const float*)d_in[7];
    const float* sd_w  = (const float*)d_in[8];
    const float* sd_b  = (const float*)d_in[9];

    int Mpts = in_sizes[0] / 3;
    int blocks = (Mpts + PP - 1) / PP;
    voxel_fused_kernel<<<blocks, NT, 0, stream>>>(
        pts, times, vox, statf, dynf, temb, td_w, td_b, sd_w, sd_b,
        (float*)d_out, Mpts);
}

// Round 2
// 579.661 us; speedup vs baseline: 2.7748x; 2.7748x over previous
//
#include <hip/hip_runtime.h>
#include <math.h>

#define DD   120
#define KPAD 128
#define KP   136          // LDS row stride in bf16 elements (272 B: 2-way bank alias = free)
#define MT   64           // points per block
#define NTHR 512          // 8 waves; wave w owns N-tile w
#define HASH_MASK 1048575LL
#define MODT 201

typedef short  short8  __attribute__((ext_vector_type(8)));
typedef float  floatx4 __attribute__((ext_vector_type(4)));

__device__ __forceinline__ unsigned short f2b(float f) {
    __bf16 h = (__bf16)f;                       // RNE hardware cvt
    return __builtin_bit_cast(unsigned short, h);
}
__device__ __forceinline__ float b2f(unsigned short u) {
    unsigned int x = ((unsigned int)u) << 16;   // exact widening
    return __builtin_bit_cast(float, x);
}

// ---------------------------------------------------------------------------
// Pre-pass 1: weights fp32 [K=120][N=120] -> bf16 W^T padded [N=128][K=128].
// Matrices 0..3 = td_w(q,k,v,out), 4..7 = sd_w(q,k,v,out).
// ---------------------------------------------------------------------------
__global__ __launch_bounds__(256)
void prep_weights(const float* __restrict__ td_w, const float* __restrict__ sd_w,
                  unsigned short* __restrict__ wt)
{
    int idx = blockIdx.x * 256 + threadIdx.x;   // 8*128*128 = 131072 total
    int mat = idx >> 14;
    int n   = (idx >> 7) & 127;
    int k   = idx & 127;
    const float* src = (mat < 4) ? (td_w + mat * DD * DD) : (sd_w + (mat - 4) * DD * DD);
    float v = (n < DD && k < DD) ? src[k * DD + n] : 0.f;
    wt[idx] = f2b(v);
}

// ---------------------------------------------------------------------------
// Pre-pass 2: k1t[t] = te[t]@W1+b1, v1t[t] = te[t]@W2+b2 for the 201 time rows
// (fusion-1 k1/v1 depend only on the time index). bf16 [201][128].
// ---------------------------------------------------------------------------
__global__ __launch_bounds__(128)
void prep_te(const float* __restrict__ temb, const float* __restrict__ td_w,
             const float* __restrict__ td_b,
             unsigned short* __restrict__ k1t, unsigned short* __restrict__ v1t)
{
    int t = blockIdx.x;      // 0..200
    int n = threadIdx.x;     // 0..127
    float a1 = 0.f, a2 = 0.f;
    if (n < DD) {
        a1 = td_b[DD + n];
        a2 = td_b[2 * DD + n];
        const float* te = temb + t * DD;
        const float* w1 = td_w + 1 * DD * DD;
        const float* w2 = td_w + 2 * DD * DD;
        for (int k = 0; k < DD; k++) {
            float x = te[k];
            a1 = fmaf(x, w1[k * DD + n], a1);
            a2 = fmaf(x, w2[k * DD + n], a2);
        }
    }
    k1t[t * KPAD + n] = f2b(a1);
    v1t[t * KPAD + n] = f2b(a2);
}

// ---------------------------------------------------------------------------
// One GEMM pass: OUT[64 x 128] = IN[64 x 128] @ W + bias, this wave's N-tile.
// A frag: lane holds IN[m=lane&15][k=quad*8..+8]  (ds_read_b128)
// B frag: lane holds W^T[n=lane&15][k=quad*8..+8] (global 16B load, L2-hot)
// C:      col = lane&15, row = quad*4 + reg       [m89-verified layout]
// ---------------------------------------------------------------------------
__device__ __forceinline__ void gemm_tile(const unsigned short* IN,
                                          const unsigned short* __restrict__ WT,
                                          const float* __restrict__ bias,
                                          unsigned short* OUT,
                                          int lm, int lq, int n0)
{
    const int n = n0 + lm;
    short8 bfr[4];
#pragma unroll
    for (int ks = 0; ks < 4; ks++)
        bfr[ks] = *(const short8*)(WT + n * KPAD + ks * 32 + lq * 8);
    float bv = (n < DD) ? bias[n] : 0.f;
#pragma unroll
    for (int mt = 0; mt < 4; mt++) {
        floatx4 acc = {0.f, 0.f, 0.f, 0.f};
#pragma unroll
        for (int ks = 0; ks < 4; ks++) {
            short8 a = *(const short8*)(IN + (mt * 16 + lm) * KP + ks * 32 + lq * 8);
            acc = __builtin_amdgcn_mfma_f32_16x16x32_bf16(a, bfr[ks], acc, 0, 0, 0);
        }
#pragma unroll
        for (int r = 0; r < 4; r++)
            OUT[(mt * 16 + lq * 4 + r) * KP + n] = f2b(acc[r] + bv);
    }
}

// Final pass: same GEMM but fp32 store straight to global, masked by valid.
__device__ __forceinline__ void gemm_out(const unsigned short* IN,
                                         const unsigned short* __restrict__ WT,
                                         const float* __restrict__ bias,
                                         float* __restrict__ out,
                                         const int* s_valid, int pbase, int Mpts,
                                         int lm, int lq, int n0)
{
    const int n = n0 + lm;
    short8 bfr[4];
#pragma unroll
    for (int ks = 0; ks < 4; ks++)
        bfr[ks] = *(const short8*)(WT + n * KPAD + ks * 32 + lq * 8);
    float bv = (n < DD) ? bias[n] : 0.f;
#pragma unroll
    for (int mt = 0; mt < 4; mt++) {
        floatx4 acc = {0.f, 0.f, 0.f, 0.f};
#pragma unroll
        for (int ks = 0; ks < 4; ks++) {
            short8 a = *(const short8*)(IN + (mt * 16 + lm) * KP + ks * 32 + lq * 8);
            acc = __builtin_amdgcn_mfma_f32_16x16x32_bf16(a, bfr[ks], acc, 0, 0, 0);
        }
        if (n < DD) {
#pragma unroll
            for (int r = 0; r < 4; r++) {
                int row = mt * 16 + lq * 4 + r;
                int gp = pbase + row;
                if (gp < Mpts)
                    out[(size_t)gp * DD + n] = s_valid[row] ? (acc[r] + bv) : 0.f;
            }
        }
    }
}

// 2-token attention, elementwise: thread = (point p, head h), 64*8 = 512 = NTHR.
__device__ __forceinline__ void attn(const unsigned short* Q, const unsigned short* K0,
                                     const unsigned short* K1, const unsigned short* V0,
                                     const unsigned short* V1, unsigned short* DEST,
                                     int tid)
{
    int p = tid >> 3, h = tid & 7;
    int base = p * KP + h * 15;
    float s0 = 0.f, s1 = 0.f;
#pragma unroll
    for (int j = 0; j < 15; j++) {
        float q = b2f(Q[base + j]);
        s0 = fmaf(q, b2f(K0[base + j]), s0);
        s1 = fmaf(q, b2f(K1[base + j]), s1);
    }
    const float scale = 0.2581988897471611f;   // 1/sqrt(15)
    s0 *= scale; s1 *= scale;
    float mx = fmaxf(s0, s1);
    float e0 = expf(s0 - mx), e1 = expf(s1 - mx);
    float p0 = e0 / (e0 + e1);
#pragma unroll
    for (int j = 0; j < 15; j++) {
        int nn = p * KP + h * 15 + j;
        float v = p0 * b2f(V0[nn]) + (1.f - p0) * b2f(V1[nn]);
        DEST[nn] = f2b(v);
    }
    // zero the K-pad cols 120..127 so DEST is a clean A-operand
    if (h == 0) *(uint4*)(DEST + p * KP + 120) = make_uint4(0u, 0u, 0u, 0u);
}

__global__ __launch_bounds__(NTHR, 1)
void voxel_mfma_kernel(const float* __restrict__ pts,
                       const int* __restrict__ times,
                       const int* __restrict__ vox_buf,
                       const float* __restrict__ stat_f,
                       const float* __restrict__ dyn_f,
                       const float* __restrict__ td_b,
                       const float* __restrict__ sd_b,
                       const unsigned short* __restrict__ wt,
                       const unsigned short* __restrict__ k1t,
                       const unsigned short* __restrict__ v1t,
                       float* __restrict__ out,
                       int Mpts)
{
    __shared__ __align__(16) unsigned short A [MT * KP];
    __shared__ __align__(16) unsigned short P1[MT * KP];
    __shared__ __align__(16) unsigned short P2[MT * KP];
    __shared__ __align__(16) unsigned short P3[MT * KP];
    __shared__ __align__(16) unsigned short P4[MT * KP];
    __shared__ __align__(16) unsigned short P5[MT * KP];
    __shared__ int s_vi[MT];
    __shared__ int s_valid[MT];
    __shared__ int s_ti[MT];

    const int tid = threadIdx.x;
    const int lane = tid & 63;
    const int lm = lane & 15;
    const int lq = lane >> 4;
    const int n0 = (tid >> 6) * 16;       // wave id * 16
    const int pbase = blockIdx.x * MT;

    // ---- per-point meta ----------------------------------------------------
    if (tid < MT) {
        int p = pbase + tid;
        int vi = 0, valid = 0, ti = 0;
        if (p < Mpts) {
            float x = pts[3 * p + 0];
            float y = pts[3 * p + 1];
            float z = pts[3 * p + 2];
            long long gx = (long long)floorf(x / 0.1f);
            long long gy = (long long)floorf(y / 0.1f);
            long long gz = (long long)floorf(z / 0.1f);
            long long hh = (gx * 73856093LL + gy * 19349669LL + gz * 83492791LL) & HASH_MASK;
            int v = vox_buf[(int)hh];
            valid = (v >= 0) ? 1 : 0;
            vi = (v >= 0) ? v : 0;
            ti = times[p] % MODT;
        }
        s_vi[tid] = vi; s_valid[tid] = valid; s_ti[tid] = ti;
    }
    // zero A's K-pad (cols 120..127) once; later writers keep it zero
    if (tid < MT * 2) {
        int p = tid >> 1, hh = tid & 1;
        *(uint2*)(A + p * KP + 120 + hh * 4) = make_uint2(0u, 0u);
    }
    __syncthreads();

    // ---- gather: df -> A (fp32->bf16); k1t -> P4, v1t -> P5 (bf16 copy) ----
    for (int i = tid; i < MT * 30; i += NTHR) {
        int p = i / 30, f = i % 30;
        float4 v = *(const float4*)(dyn_f + (size_t)s_vi[p] * DD + f * 4);
        unsigned int lo = (unsigned int)f2b(v.x) | ((unsigned int)f2b(v.y) << 16);
        unsigned int hi = (unsigned int)f2b(v.z) | ((unsigned int)f2b(v.w) << 16);
        *(uint2*)(A + p * KP + f * 4) = make_uint2(lo, hi);
    }
    for (int i = tid; i < MT * 16; i += NTHR) {
        int p = i >> 4, f = i & 15;
        *(uint4*)(P4 + p * KP + f * 8) = *(const uint4*)(k1t + s_ti[p] * KPAD + f * 8);
        *(uint4*)(P5 + p * KP + f * 8) = *(const uint4*)(v1t + s_ti[p] * KPAD + f * 8);
    }
    __syncthreads();

    // ---- fusion 1: q,k0,v0 from df ----------------------------------------
    gemm_tile(A, wt + 0 * 16384, td_b + 0,   P1, lm, lq, n0);  // Q
    gemm_tile(A, wt + 1 * 16384, td_b + 120, P2, lm, lq, n0);  // K0
    gemm_tile(A, wt + 2 * 16384, td_b + 240, P3, lm, lq, n0);  // V0
    __syncthreads();

    attn(P1, P2, P4, P3, P5, A, tid);        // o -> A (df dead)
    __syncthreads();

    gemm_tile(A, wt + 3 * 16384, td_b + 360, P1, lm, lq, n0);  // cond -> P1
    __syncthreads();

    // ---- gather sf -> A ----------------------------------------------------
    for (int i = tid; i < MT * 30; i += NTHR) {
        int p = i / 30, f = i % 30;
        float4 v = *(const float4*)(stat_f + (size_t)s_vi[p] * DD + f * 4);
        unsigned int lo = (unsigned int)f2b(v.x) | ((unsigned int)f2b(v.y) << 16);
        unsigned int hi = (unsigned int)f2b(v.z) | ((unsigned int)f2b(v.w) << 16);
        *(uint2*)(A + p * KP + f * 4) = make_uint2(lo, hi);
    }
    __syncthreads();

    // ---- fusion 2 projections ---------------------------------------------
    gemm_tile(A,  wt + 4 * 16384, sd_b + 0,   P2, lm, lq, n0); // Q
    gemm_tile(A,  wt + 5 * 16384, sd_b + 120, P3, lm, lq, n0); // K0
    gemm_tile(A,  wt + 6 * 16384, sd_b + 240, P4, lm, lq, n0); // V0
    gemm_tile(P1, wt + 5 * 16384, sd_b + 120, P5, lm, lq, n0); // K1 = cond@U1
    __syncthreads();
    gemm_tile(P1, wt + 6 * 16384, sd_b + 240, A,  lm, lq, n0); // V1 = cond@U2 (sf dead)
    __syncthreads();

    attn(P2, P3, P5, P4, A, P1, tid);        // o2 -> P1 (cond dead)
    __syncthreads();

    // ---- final: out = o2 @ U3 + b, masked ---------------------------------
    gemm_out(P1, wt + 7 * 16384, sd_b + 360, out, s_valid, pbase, Mpts, lm, lq, n0);
}

extern "C" void kernel_launch(void* const* d_in, const int* in_sizes, int n_in,
                              void* d_out, int out_size, void* d_ws, size_t ws_size,
                              hipStream_t stream) {
    const float* pts   = (const float*)d_in[0];
    const int*   times = (const int*)d_in[1];
    const int*   vox   = (const int*)d_in[2];
    const float* statf = (const float*)d_in[3];
    const float* dynf  = (const float*)d_in[4];
    const float* temb  = (const float*)d_in[5];
    const float* td_w  = (const float*)d_in[6];
    const float* td_b  = (const float*)d_in[7];
    const float* sd_w  = (const float*)d_in[8];
    const float* sd_b  = (const float*)d_in[9];

    unsigned short* wt  = (unsigned short*)d_ws;          // 8*128*128 bf16 = 256 KB
    unsigned short* k1t = wt + 8 * 128 * 128;             // 201*128 bf16
    unsigned short* v1t = k1t + 201 * 128;                // 201*128 bf16

    prep_weights<<<512, 256, 0, stream>>>(td_w, sd_w, wt);
    prep_te<<<201, 128, 0, stream>>>(temb, td_w, td_b, k1t, v1t);

    int Mpts = in_sizes[0] / 3;
    int blocks = (Mpts + MT - 1) / MT;
    voxel_mfma_kernel<<<blocks, NTHR, 0, stream>>>(
        pts, times, vox, statf, dynf, td_b, sd_b, wt, k1t, v1t,
        (float*)d_out, Mpts);
}